// Round 1
// baseline (44213.062 us; speedup 1.0000x reference)
//
#include <hip/hip_runtime.h>

typedef __attribute__((ext_vector_type(8))) short bf16x8;
typedef __attribute__((ext_vector_type(4))) float f32x4;

#define T_SEQ 2048
#define RING  64
#define NL0   32
#define NL1   32
#define NFC   8
#define NWG   (NL0 + NL1 + NFC)

__device__ __forceinline__ unsigned short f2b(float f) {
  unsigned u = __float_as_uint(f);
  u = (u + 0x7fffu + ((u >> 16) & 1u)) >> 16;
  return (unsigned short)u;
}
__device__ __forceinline__ float sigm(float x) { return 1.f / (1.f + __expf(-x)); }
__device__ __forceinline__ float tanh_f(float x) { return 2.f / (1.f + __expf(-2.f * x)) - 1.f; }

__device__ __forceinline__ void wg_wait(const int* cnt, int target) {
  if (threadIdx.x == 0) {
    while (__hip_atomic_load(cnt, __ATOMIC_ACQUIRE, __HIP_MEMORY_SCOPE_AGENT) < target)
      __builtin_amdgcn_s_sleep(1);
  }
  __syncthreads();
}
__device__ __forceinline__ void wg_publish(int* cnt) {
  __threadfence();        // make this thread's prior writes device-visible
  __syncthreads();        // everyone fenced before the flag moves
  if (threadIdx.x == 0)
    __hip_atomic_fetch_add(cnt, 1, __ATOMIC_RELEASE, __HIP_MEMORY_SCOPE_AGENT);
}

// ---------------- prologue: pack weights bf16, transpose x, zero state ----------------
__global__ void lstm_prologue(
    const float* __restrict__ x, const float* __restrict__ wih0, const float* __restrict__ whh0,
    const float* __restrict__ wih1, const float* __restrict__ whh1, const float* __restrict__ wfc,
    unsigned short* __restrict__ wl0, unsigned short* __restrict__ wl1,
    unsigned short* __restrict__ wfcp, unsigned short* __restrict__ xb,
    unsigned short* __restrict__ h0r, unsigned short* __restrict__ h1r,
    int* __restrict__ c0, int* __restrict__ c1, int* __restrict__ cf) {
  size_t tid = (size_t)blockIdx.x * blockDim.x + threadIdx.x;
  size_t nthr = (size_t)gridDim.x * blockDim.x;
  // wl0: [2048][768] = [w_ih0 row (256) | w_hh0 row (512)]
  for (size_t i = tid; i < (size_t)2048 * 768; i += nthr) {
    int r = (int)(i / 768), k = (int)(i % 768);
    float v = (k < 256) ? wih0[(size_t)r * 256 + k] : whh0[(size_t)r * 512 + (k - 256)];
    wl0[i] = f2b(v);
  }
  // wl1: [2048][1024] = [w_ih1 row (512) | w_hh1 row (512)]
  for (size_t i = tid; i < (size_t)2048 * 1024; i += nthr) {
    int r = (int)(i >> 10), k = (int)(i & 1023);
    float v = (k < 512) ? wih1[((size_t)r << 9) + k] : whh1[((size_t)r << 9) + (k - 512)];
    wl1[i] = f2b(v);
  }
  for (size_t i = tid; i < 131072; i += nthr) wfcp[i] = f2b(wfc[i]);
  // xb: [T][B][256] bf16, from x [B][T][256] f32
  for (size_t i = tid; i < (size_t)16777216; i += nthr) {
    int ii = (int)(i & 255), b = (int)((i >> 8) & 31), t = (int)(i >> 13);
    xb[i] = f2b(x[((size_t)b * 2048 + t) * 256 + ii]);
  }
  for (size_t i = tid; i < 2048; i += nthr) { c0[i] = 0; c1[i] = 0; cf[i] = 0; }
  // zero ring slot for t = -1 (slot RING-1)
  for (size_t i = tid; i < 32 * 512; i += nthr) {
    h0r[(size_t)(RING - 1) * 32 * 512 + i] = 0;
    h1r[(size_t)(RING - 1) * 32 * 512 + i] = 0;
  }
}

// ---------------- main persistent pipelined kernel ----------------
__global__ void __launch_bounds__(256, 1) lstm_main(
    const unsigned short* __restrict__ xb,
    const unsigned short* __restrict__ wl0,
    const unsigned short* __restrict__ wl1,
    const unsigned short* __restrict__ wfcp,
    const float* __restrict__ b0,
    const float* __restrict__ b1,
    const float* __restrict__ bfc,
    unsigned short* __restrict__ h0r,
    unsigned short* __restrict__ h1r,
    int* c0, int* c1, int* cf,
    float* __restrict__ out) {
  __shared__ __align__(16) float gates[4][16][32];  // [gate][unit][batch]
  __shared__ __align__(16) float cst[16][32];       // cell state [unit][batch]
  const int tid = threadIdx.x;
  const int wave = tid >> 6;
  const int lane = tid & 63;
  const int l15 = lane & 15;
  const int kgrp = lane >> 4;
  const int wid = blockIdx.x;

  if (wid < NL0 + NL1) {
    const bool isL0 = wid < NL0;
    const int u0 = (isL0 ? wid : wid - NL0) * 16;
    for (int i = tid; i < 16 * 32; i += 256) ((float*)cst)[i] = 0.f;
    __syncthreads();

    const int K = isL0 ? 768 : 1024;
    const unsigned short* wbase = isL0 ? wl0 : wl1;
    const float* bias = isL0 ? b0 : b1;
    const unsigned short* wrow = wbase + (size_t)(wave * 512 + u0 + l15) * K;
    unsigned short* hw = isL0 ? h0r : h1r;
    const int s0len = isL0 ? 256 : 512;
    const int nk0 = isL0 ? 8 : 16;
    const int nk = isL0 ? 24 : 32;

    const float bi = bias[0 * 512 + u0 + (tid & 15)];
    const float bf_ = bias[1 * 512 + u0 + (tid & 15)];
    const float bg = bias[2 * 512 + u0 + (tid & 15)];
    const float bo = bias[3 * 512 + u0 + (tid & 15)];

    for (int t = 0; t < T_SEQ; ++t) {
      if (isL0) {
        if (t > 0) wg_wait(&c0[t - 1], NL0);
        if (t >= RING) wg_wait(&c1[t - RING], NL1);  // h0[t-RING] consumers done
      } else {
        wg_wait(&c0[t], NL0);
        if (t > 0) wg_wait(&c1[t - 1], NL1);
        if (t >= RING) wg_wait(&cf[t - RING], NFC);  // h1[t-RING] consumers done
      }
      const unsigned short* hprev =
          (isL0 ? h0r : h1r) + (size_t)((t - 1) & (RING - 1)) * (32 * 512);
      const unsigned short* src0 =
          isL0 ? (xb + (size_t)t * 32 * 256)
               : (h0r + (size_t)(t & (RING - 1)) * (32 * 512));

      f32x4 acc0 = {0.f, 0.f, 0.f, 0.f}, acc1 = {0.f, 0.f, 0.f, 0.f};
      for (int kk = 0; kk < nk; ++kk) {
        const int k0 = kk * 32 + kgrp * 8;
        bf16x8 bfrag = *(const bf16x8*)(wrow + k0);
        const unsigned short* abase;
        int koff, rs;
        if (kk < nk0) { abase = src0; koff = k0; rs = s0len; }
        else          { abase = hprev; koff = k0 - s0len; rs = 512; }
        bf16x8 a0 = *(const bf16x8*)(abase + (size_t)l15 * rs + koff);
        bf16x8 a1 = *(const bf16x8*)(abase + (size_t)(16 + l15) * rs + koff);
        acc0 = __builtin_amdgcn_mfma_f32_16x16x32_bf16(a0, bfrag, acc0, 0, 0, 0);
        acc1 = __builtin_amdgcn_mfma_f32_16x16x32_bf16(a1, bfrag, acc1, 0, 0, 0);
      }
      // C/D layout: col(lane&15) = gate-row (unit), row((lane>>4)*4+j) = batch
      *(f32x4*)&gates[wave][l15][kgrp * 4] = acc0;
      *(f32x4*)&gates[wave][l15][16 + kgrp * 4] = acc1;
      __syncthreads();

      const int u = tid & 15;
      const int b_lo = tid >> 4;
      unsigned short* hdst = hw + (size_t)(t & (RING - 1)) * (32 * 512);
#pragma unroll
      for (int bb = 0; bb < 2; ++bb) {
        int b = b_lo + bb * 16;
        float i_ = sigm(gates[0][u][b] + bi);
        float f_ = sigm(gates[1][u][b] + bf_);
        float g_ = tanh_f(gates[2][u][b] + bg);
        float o_ = sigm(gates[3][u][b] + bo);
        float c = f_ * cst[u][b] + i_ * g_;
        cst[u][b] = c;
        hdst[(size_t)b * 512 + u0 + u] = f2b(o_ * tanh_f(c));
      }
      if (isL0) wg_publish(&c0[t]); else wg_publish(&c1[t]);
    }
  } else {
    // ---- FC stage: 8 WGs x 32 output rows ----
    const int r0 = (wid - NL0 - NL1) * 32;
    const int mt = wave >> 1, ntile = wave & 1;
    const int orow = r0 + ntile * 16 + l15;
    const unsigned short* wrow = wfcp + (size_t)orow * 512;
    const float bb = bfc[orow];
    for (int t = 0; t < T_SEQ; ++t) {
      wg_wait(&c1[t], NL1);
      const unsigned short* hcur = h1r + (size_t)(t & (RING - 1)) * (32 * 512);
      f32x4 acc = {0.f, 0.f, 0.f, 0.f};
      for (int kk = 0; kk < 16; ++kk) {
        int k0 = kk * 32 + kgrp * 8;
        bf16x8 bfrag = *(const bf16x8*)(wrow + k0);
        bf16x8 a = *(const bf16x8*)(hcur + (size_t)(mt * 16 + l15) * 512 + k0);
        acc = __builtin_amdgcn_mfma_f32_16x16x32_bf16(a, bfrag, acc, 0, 0, 0);
      }
#pragma unroll
      for (int j = 0; j < 4; ++j) {
        int b = mt * 16 + kgrp * 4 + j;
        out[((size_t)b * T_SEQ + t) * 256 + orow] = acc[j] + bb;
      }
      wg_publish(&cf[t]);
    }
  }
}

extern "C" void kernel_launch(void* const* d_in, const int* in_sizes, int n_in,
                              void* d_out, int out_size, void* d_ws, size_t ws_size,
                              hipStream_t stream) {
  const float* x    = (const float*)d_in[0];
  const float* wih0 = (const float*)d_in[1];
  const float* whh0 = (const float*)d_in[2];
  const float* b0   = (const float*)d_in[3];
  const float* wih1 = (const float*)d_in[4];
  const float* whh1 = (const float*)d_in[5];
  const float* b1   = (const float*)d_in[6];
  const float* wfc  = (const float*)d_in[7];
  const float* bfc  = (const float*)d_in[8];
  float* outp = (float*)d_out;

  char* ws = (char*)d_ws;
  size_t off = 0;
  unsigned short* wl0p  = (unsigned short*)(ws + off); off += (size_t)2048 * 768 * 2;
  unsigned short* wl1p  = (unsigned short*)(ws + off); off += (size_t)2048 * 1024 * 2;
  unsigned short* wfcp  = (unsigned short*)(ws + off); off += (size_t)256 * 512 * 2;
  unsigned short* xbp   = (unsigned short*)(ws + off); off += (size_t)2048 * 32 * 256 * 2;
  unsigned short* h0rp  = (unsigned short*)(ws + off); off += (size_t)RING * 32 * 512 * 2;
  unsigned short* h1rp  = (unsigned short*)(ws + off); off += (size_t)RING * 32 * 512 * 2;
  int* c0p = (int*)(ws + off); off += 2048 * sizeof(int);
  int* c1p = (int*)(ws + off); off += 2048 * sizeof(int);
  int* cfp = (int*)(ws + off); off += 2048 * sizeof(int);

  lstm_prologue<<<dim3(1024), dim3(256), 0, stream>>>(
      x, wih0, whh0, wih1, whh1, wfc, wl0p, wl1p, wfcp, xbp, h0rp, h1rp, c0p, c1p, cfp);

  void* args[] = {
      (void*)&xbp, (void*)&wl0p, (void*)&wl1p, (void*)&wfcp,
      (void*)&b0, (void*)&b1, (void*)&bfc,
      (void*)&h0rp, (void*)&h1rp,
      (void*)&c0p, (void*)&c1p, (void*)&cfp,
      (void*)&outp};
  hipLaunchCooperativeKernel(lstm_main, dim3(NWG), dim3(256), args, 0, stream);
}

// Round 2
// 16195.784 us; speedup vs baseline: 2.7299x; 2.7299x over previous
//
#include <hip/hip_runtime.h>

typedef __attribute__((ext_vector_type(8))) short bf16x8;
typedef __attribute__((ext_vector_type(4))) float f32x4;
typedef __attribute__((ext_vector_type(4))) unsigned int u32x4;

#define T_SEQ 2048
#define RING  64
#define NL0   32
#define NL1   32
#define NFC   8
#define NWG   (NL0 + NL1 + NFC)

// XOR swizzle for 1024B-row-stride LDS tiles (spreads 8 rows over 8 16B slots)
#define HSWZ(o) ((o) ^ ((((o) >> 10) & 7) << 4))

static __device__ __forceinline__ unsigned short f2b(float f) {
  unsigned u = __float_as_uint(f);
  u = (u + 0x7fffu + ((u >> 16) & 1u)) >> 16;
  return (unsigned short)u;
}
static __device__ __forceinline__ float sigm(float x) { return 1.f / (1.f + __expf(-x)); }
static __device__ __forceinline__ float tanh_f(float x) { return 2.f / (1.f + __expf(-2.f * x)) - 1.f; }

// ---- LLC-coherent (cross-XCD) data movement: no L2 maintenance ops ----
static __device__ __forceinline__ u32x4 llc_load16(const void* p) {
  u32x4 v;
  asm volatile("global_load_dwordx4 %0, %1, off sc0 sc1" : "=v"(v) : "v"(p) : "memory");
  return v;
}
static __device__ __forceinline__ void llc_store4(void* p, unsigned v) {
  asm volatile("global_store_dword %0, %1, off sc0 sc1" :: "v"(p), "v"(v) : "memory");
}
static __device__ __forceinline__ void vmwait() {
  asm volatile("s_waitcnt vmcnt(0)" ::: "memory");
}

// relaxed system-scope flag ops: no buffer_inv / buffer_wbl2 emitted
static __device__ __forceinline__ void flag_wait3(const int* a, int ta,
                                                  const int* b, int tb,
                                                  const int* c, int tc) {
  if (threadIdx.x == 0) {
    int va, vb, vc;
    do {  // three loads issue back-to-back -> one LLC latency per poll round
      va = __hip_atomic_load(a, __ATOMIC_RELAXED, __HIP_MEMORY_SCOPE_SYSTEM);
      vb = __hip_atomic_load(b, __ATOMIC_RELAXED, __HIP_MEMORY_SCOPE_SYSTEM);
      vc = __hip_atomic_load(c, __ATOMIC_RELAXED, __HIP_MEMORY_SCOPE_SYSTEM);
    } while (va < ta || vb < tb || vc < tc);
  }
  __syncthreads();
}
static __device__ __forceinline__ void flag_add(int* c) {
  __hip_atomic_fetch_add(c, 1, __ATOMIC_RELAXED, __HIP_MEMORY_SCOPE_SYSTEM);
}

// ---------------- prologue: pack weights bf16, transpose x, zero state ----------------
__global__ void lstm_prologue(
    const float* __restrict__ x, const float* __restrict__ wih0, const float* __restrict__ whh0,
    const float* __restrict__ wih1, const float* __restrict__ whh1, const float* __restrict__ wfc,
    unsigned short* __restrict__ wl0, unsigned short* __restrict__ wl1,
    unsigned short* __restrict__ wfcp, unsigned short* __restrict__ xb,
    unsigned short* __restrict__ h0r, unsigned short* __restrict__ h1r,
    int* __restrict__ c0, int* __restrict__ c1, int* __restrict__ cf) {
  size_t tid = (size_t)blockIdx.x * blockDim.x + threadIdx.x;
  size_t nthr = (size_t)gridDim.x * blockDim.x;
  for (size_t i = tid; i < (size_t)2048 * 768; i += nthr) {
    int r = (int)(i / 768), k = (int)(i % 768);
    float v = (k < 256) ? wih0[(size_t)r * 256 + k] : whh0[(size_t)r * 512 + (k - 256)];
    wl0[i] = f2b(v);
  }
  for (size_t i = tid; i < (size_t)2048 * 1024; i += nthr) {
    int r = (int)(i >> 10), k = (int)(i & 1023);
    float v = (k < 512) ? wih1[((size_t)r << 9) + k] : whh1[((size_t)r << 9) + (k - 512)];
    wl1[i] = f2b(v);
  }
  for (size_t i = tid; i < 131072; i += nthr) wfcp[i] = f2b(wfc[i]);
  // xb: [T][B][256] bf16 from x [B][T][256] f32
  for (size_t i = tid; i < (size_t)16777216; i += nthr) {
    int ii = (int)(i & 255), b = (int)((i >> 8) & 31), t = (int)(i >> 13);
    xb[i] = f2b(x[((size_t)b * 2048 + t) * 256 + ii]);
  }
  for (size_t i = tid; i < 2048; i += nthr) { c0[i] = 0; c1[i] = 0; cf[i] = 0; }
  for (size_t i = tid; i < 32 * 512; i += nthr) {
    h0r[(size_t)(RING - 1) * 32 * 512 + i] = 0;
    h1r[(size_t)(RING - 1) * 32 * 512 + i] = 0;
  }
}

// ---------------- LSTM layer workgroup body ----------------
template <int ISL0>
static __device__ void lstm_path(
    const unsigned short* __restrict__ xb, const unsigned short* __restrict__ wl,
    const float* __restrict__ bias,
    unsigned short* __restrict__ h0r, unsigned short* __restrict__ h1r,
    int* c0, int* c1, int* cf, int wid2,
    unsigned short* hA, unsigned short* xA, float (*gates)[32][18]) {
  const int tid = threadIdx.x;
  const int wave = tid >> 6, lane = tid & 63, l15 = lane & 15, kgrp = lane >> 4;
  const int u0 = wid2 * 16;
  constexpr int K = ISL0 ? 768 : 1024;
  const unsigned short* wrow = wl + (size_t)(wave * 512 + u0 + l15) * K;

  const int ue = 2 * (tid & 7);  // epilogue unit pair
  const int be = tid >> 3;       // epilogue batch
  const float bi0 = bias[0 * 512 + u0 + ue], bi1 = bias[0 * 512 + u0 + ue + 1];
  const float bf0 = bias[1 * 512 + u0 + ue], bf1 = bias[1 * 512 + u0 + ue + 1];
  const float bg0 = bias[2 * 512 + u0 + ue], bg1 = bias[2 * 512 + u0 + ue + 1];
  const float bo0 = bias[3 * 512 + u0 + ue], bo1 = bias[3 * 512 + u0 + ue + 1];
  float cc0 = 0.f, cc1 = 0.f;
  unsigned short* myring = ISL0 ? h0r : h1r;

  for (int t = 0; t < T_SEQ; ++t) {
    if (ISL0) {
      flag_wait3(t > 0 ? &c0[t - 1] : &c0[0], t > 0 ? NL0 : 0,
                 t >= RING ? &c1[t - RING] : &c1[0], t >= RING ? NL1 : 0,
                 &c0[0], 0);
    } else {
      flag_wait3(&c0[t], NL0,
                 t > 0 ? &c1[t - 1] : &c1[0], t > 0 ? NL1 : 0,
                 t >= RING ? &cf[t - RING] : &cf[0], t >= RING ? NFC : 0);
    }

    // ---- stage h tiles LDS <- LLC (one batched latency) ----
    const unsigned short* hprev = myring + (size_t)((t - 1) & (RING - 1)) * (32 * 512);
    u32x4 th[8], tx[8];
#pragma unroll
    for (int k = 0; k < 8; ++k)
      th[k] = llc_load16((const char*)hprev + (size_t)(tid + k * 256) * 16);
    if (!ISL0) {
      const unsigned short* h0cur = h0r + (size_t)(t & (RING - 1)) * (32 * 512);
#pragma unroll
      for (int k = 0; k < 8; ++k)
        tx[k] = llc_load16((const char*)h0cur + (size_t)(tid + k * 256) * 16);
    }
    vmwait();
#pragma unroll
    for (int k = 0; k < 8; ++k) {
      int off = (tid + k * 256) * 16;
      *(u32x4*)((char*)hA + HSWZ(off)) = th[k];
    }
    if (!ISL0) {
#pragma unroll
      for (int k = 0; k < 8; ++k) {
        int off = (tid + k * 256) * 16;
        *(u32x4*)((char*)xA + HSWZ(off)) = tx[k];
      }
    }
    __syncthreads();

    // ---- gates = [x|h0] @ Wih^T + h_prev @ Whh^T ----
    f32x4 acc0 = {0.f, 0.f, 0.f, 0.f}, acc1 = {0.f, 0.f, 0.f, 0.f};
    if (ISL0) {
      const unsigned short* xt = xb + (size_t)t * (32 * 256);
#pragma unroll
      for (int kk = 0; kk < 8; ++kk) {  // x-part: plain L2-cached loads
        int k0 = kk * 32 + kgrp * 8;
        bf16x8 bfrag = *(const bf16x8*)(wrow + k0);
        bf16x8 a0 = *(const bf16x8*)(xt + l15 * 256 + k0);
        bf16x8 a1 = *(const bf16x8*)(xt + (16 + l15) * 256 + k0);
        acc0 = __builtin_amdgcn_mfma_f32_16x16x32_bf16(a0, bfrag, acc0, 0, 0, 0);
        acc1 = __builtin_amdgcn_mfma_f32_16x16x32_bf16(a1, bfrag, acc1, 0, 0, 0);
      }
#pragma unroll
      for (int kk = 0; kk < 16; ++kk) {  // h-part from LDS
        int k0 = kk * 32 + kgrp * 8;
        bf16x8 bfrag = *(const bf16x8*)(wrow + 256 + k0);
        int cb = k0 * 2;
        bf16x8 a0 = *(const bf16x8*)((const char*)hA + HSWZ(l15 * 1024 + cb));
        bf16x8 a1 = *(const bf16x8*)((const char*)hA + HSWZ((16 + l15) * 1024 + cb));
        acc0 = __builtin_amdgcn_mfma_f32_16x16x32_bf16(a0, bfrag, acc0, 0, 0, 0);
        acc1 = __builtin_amdgcn_mfma_f32_16x16x32_bf16(a1, bfrag, acc1, 0, 0, 0);
      }
    } else {
#pragma unroll
      for (int kk = 0; kk < 16; ++kk) {  // h0-part from LDS
        int k0 = kk * 32 + kgrp * 8;
        bf16x8 bfrag = *(const bf16x8*)(wrow + k0);
        int cb = k0 * 2;
        bf16x8 a0 = *(const bf16x8*)((const char*)xA + HSWZ(l15 * 1024 + cb));
        bf16x8 a1 = *(const bf16x8*)((const char*)xA + HSWZ((16 + l15) * 1024 + cb));
        acc0 = __builtin_amdgcn_mfma_f32_16x16x32_bf16(a0, bfrag, acc0, 0, 0, 0);
        acc1 = __builtin_amdgcn_mfma_f32_16x16x32_bf16(a1, bfrag, acc1, 0, 0, 0);
      }
#pragma unroll
      for (int kk = 0; kk < 16; ++kk) {  // h1-prev part from LDS
        int k0 = kk * 32 + kgrp * 8;
        bf16x8 bfrag = *(const bf16x8*)(wrow + 512 + k0);
        int cb = k0 * 2;
        bf16x8 a0 = *(const bf16x8*)((const char*)hA + HSWZ(l15 * 1024 + cb));
        bf16x8 a1 = *(const bf16x8*)((const char*)hA + HSWZ((16 + l15) * 1024 + cb));
        acc0 = __builtin_amdgcn_mfma_f32_16x16x32_bf16(a0, bfrag, acc0, 0, 0, 0);
        acc1 = __builtin_amdgcn_mfma_f32_16x16x32_bf16(a1, bfrag, acc1, 0, 0, 0);
      }
    }
    // C/D: col(l15)=unit, row(kgrp*4+j)=batch.  gates[gate][batch][unit]
#pragma unroll
    for (int j = 0; j < 4; ++j) {
      gates[wave][kgrp * 4 + j][l15] = acc0[j];
      gates[wave][16 + kgrp * 4 + j][l15] = acc1[j];
    }
    __syncthreads();

    // ---- epilogue: per-thread 2 units x 1 batch; c stays in registers ----
    unsigned short* hdst = myring + (size_t)(t & (RING - 1)) * (32 * 512);
    float i0 = sigm(gates[0][be][ue] + bi0);
    float ff0 = sigm(gates[1][be][ue] + bf0);
    float g0 = tanh_f(gates[2][be][ue] + bg0);
    float o0 = sigm(gates[3][be][ue] + bo0);
    cc0 = ff0 * cc0 + i0 * g0;
    float hv0 = o0 * tanh_f(cc0);
    float i1 = sigm(gates[0][be][ue + 1] + bi1);
    float ff1 = sigm(gates[1][be][ue + 1] + bf1);
    float g1 = tanh_f(gates[2][be][ue + 1] + bg1);
    float o1 = sigm(gates[3][be][ue + 1] + bo1);
    cc1 = ff1 * cc1 + i1 * g1;
    float hv1 = o1 * tanh_f(cc1);
    unsigned pv = (unsigned)f2b(hv0) | ((unsigned)f2b(hv1) << 16);
    llc_store4(hdst + (size_t)be * 512 + u0 + ue, pv);
    vmwait();            // this thread's h visible at LLC
    __syncthreads();     // all threads' h visible
    if (tid == 0) flag_add(ISL0 ? &c0[t] : &c1[t]);
  }
}

// ---------------- main persistent pipelined kernel ----------------
__global__ void __launch_bounds__(256, 1) lstm_main(
    const unsigned short* __restrict__ xb,
    const unsigned short* __restrict__ wl0,
    const unsigned short* __restrict__ wl1,
    const unsigned short* __restrict__ wfcp,
    const float* __restrict__ b0,
    const float* __restrict__ b1,
    const float* __restrict__ bfc,
    unsigned short* __restrict__ h0r,
    unsigned short* __restrict__ h1r,
    int* c0, int* c1, int* cf,
    float* __restrict__ out) {
  __shared__ __align__(16) unsigned short hA[32 * 512];
  __shared__ __align__(16) unsigned short xA[32 * 512];
  __shared__ __align__(16) float gates[4][32][18];
  const int tid = threadIdx.x;
  const int wave = tid >> 6, lane = tid & 63, l15 = lane & 15, kgrp = lane >> 4;
  const int wid = blockIdx.x;

  if (wid < NL0) {
    lstm_path<1>(xb, wl0, b0, h0r, h1r, c0, c1, cf, wid, hA, xA, gates);
  } else if (wid < NL0 + NL1) {
    lstm_path<0>(xb, wl1, b1, h0r, h1r, c0, c1, cf, wid - NL0, hA, xA, gates);
  } else {
    const int fcw = wid - NL0 - NL1;  // 0..7
    const int mt = wave >> 1, ntile = wave & 1;
    const int orow = fcw * 32 + ntile * 16 + l15;
    const unsigned short* wrowf = wfcp + (size_t)orow * 512;
    const float bb = bfc[orow];
    for (int t = 0; t < T_SEQ; ++t) {
      flag_wait3(&c1[t], NL1, &c1[t], 0, &c1[t], 0);
      const unsigned short* hcur = h1r + (size_t)(t & (RING - 1)) * (32 * 512);
      u32x4 th[8];
#pragma unroll
      for (int k = 0; k < 8; ++k)
        th[k] = llc_load16((const char*)hcur + (size_t)(tid + k * 256) * 16);
      vmwait();
#pragma unroll
      for (int k = 0; k < 8; ++k) {
        int off = (tid + k * 256) * 16;
        *(u32x4*)((char*)hA + HSWZ(off)) = th[k];
      }
      __syncthreads();
      if (tid == 0) flag_add(&cf[t]);  // h1[t] consumed (ring guard)
      f32x4 acc = {0.f, 0.f, 0.f, 0.f};
#pragma unroll
      for (int kk = 0; kk < 16; ++kk) {
        int k0 = kk * 32 + kgrp * 8;
        bf16x8 bfrag = *(const bf16x8*)(wrowf + k0);
        int row = mt * 16 + l15;
        bf16x8 a = *(const bf16x8*)((const char*)hA + HSWZ(row * 1024 + k0 * 2));
        acc = __builtin_amdgcn_mfma_f32_16x16x32_bf16(a, bfrag, acc, 0, 0, 0);
      }
#pragma unroll
      for (int j = 0; j < 4; ++j) {
        int b = mt * 16 + kgrp * 4 + j;
        out[((size_t)b * T_SEQ + t) * 256 + orow] = acc[j] + bb;
      }
    }
  }
}

extern "C" void kernel_launch(void* const* d_in, const int* in_sizes, int n_in,
                              void* d_out, int out_size, void* d_ws, size_t ws_size,
                              hipStream_t stream) {
  const float* x    = (const float*)d_in[0];
  const float* wih0 = (const float*)d_in[1];
  const float* whh0 = (const float*)d_in[2];
  const float* b0   = (const float*)d_in[3];
  const float* wih1 = (const float*)d_in[4];
  const float* whh1 = (const float*)d_in[5];
  const float* b1   = (const float*)d_in[6];
  const float* wfc  = (const float*)d_in[7];
  const float* bfc  = (const float*)d_in[8];
  float* outp = (float*)d_out;

  char* ws = (char*)d_ws;
  size_t off = 0;
  unsigned short* wl0p = (unsigned short*)(ws + off); off += (size_t)2048 * 768 * 2;
  unsigned short* wl1p = (unsigned short*)(ws + off); off += (size_t)2048 * 1024 * 2;
  unsigned short* wfcp = (unsigned short*)(ws + off); off += (size_t)256 * 512 * 2;
  unsigned short* xbp  = (unsigned short*)(ws + off); off += (size_t)2048 * 32 * 256 * 2;
  unsigned short* h0rp = (unsigned short*)(ws + off); off += (size_t)RING * 32 * 512 * 2;
  unsigned short* h1rp = (unsigned short*)(ws + off); off += (size_t)RING * 32 * 512 * 2;
  int* c0p = (int*)(ws + off); off += 2048 * sizeof(int);
  int* c1p = (int*)(ws + off); off += 2048 * sizeof(int);
  int* cfp = (int*)(ws + off); off += 2048 * sizeof(int);

  lstm_prologue<<<dim3(1024), dim3(256), 0, stream>>>(
      x, wih0, whh0, wih1, whh1, wfc, wl0p, wl1p, wfcp, xbp, h0rp, h1rp, c0p, c1p, cfp);

  void* args[] = {
      (void*)&xbp, (void*)&wl0p, (void*)&wl1p, (void*)&wfcp,
      (void*)&b0, (void*)&b1, (void*)&bfc,
      (void*)&h0rp, (void*)&h1rp,
      (void*)&c0p, (void*)&c1p, (void*)&cfp,
      (void*)&outp};
  hipLaunchCooperativeKernel(lstm_main, dim3(NWG), dim3(256), args, 0, stream);
}

// Round 5
// 8449.166 us; speedup vs baseline: 5.2328x; 1.9168x over previous
//
#include <hip/hip_runtime.h>

typedef __attribute__((ext_vector_type(8))) short bf16x8;
typedef __attribute__((ext_vector_type(4))) float f32x4;
typedef __attribute__((ext_vector_type(4))) unsigned int u32x4;

#define T_SEQ 2048
#define RING  64
#define NL0   32
#define NL1   32
#define NFC   8
#define NWG   (NL0 + NL1 + NFC)
#define SLOT_STRIDE 16  // ints; 64B per slot to avoid store-side false sharing

// XOR swizzle for 1024B-row-stride LDS tiles (spreads 8 rows over 8 16B slots)
#define HSWZ(o) ((o) ^ ((((o) >> 10) & 7) << 4))

static __device__ __forceinline__ unsigned short f2b(float f) {
  unsigned u = __float_as_uint(f);
  u = (u + 0x7fffu + ((u >> 16) & 1u)) >> 16;
  return (unsigned short)u;
}
static __device__ __forceinline__ float sigm(float x) { return 1.f / (1.f + __expf(-x)); }
static __device__ __forceinline__ float tanh_f(float x) { return 2.f / (1.f + __expf(-2.f * x)) - 1.f; }

// ---- LLC-coherent (cross-XCD) bulk data movement (proven in round 2) ----
static __device__ __forceinline__ u32x4 llc_load16(const void* p) {
  u32x4 v;
  asm volatile("global_load_dwordx4 %0, %1, off sc0 sc1" : "=v"(v) : "v"(p) : "memory");
  return v;
}
static __device__ __forceinline__ void llc_store4(void* p, unsigned v) {
  asm volatile("global_store_dword %0, %1, off sc0 sc1" :: "v"(p), "v"(v) : "memory");
}
static __device__ __forceinline__ void vmwait() {
  asm volatile("s_waitcnt vmcnt(0)" ::: "memory");
}

// Flag ops: compiler-generated relaxed system-scope atomics (no RMW, no
// L2 maintenance; compiler handles waitcnt insertion — round-2-proven class).
static __device__ __forceinline__ int flag_ld(const int* p) {
  return __hip_atomic_load(p, __ATOMIC_RELAXED, __HIP_MEMORY_SCOPE_SYSTEM);
}
static __device__ __forceinline__ void flag_st(int* p, int v) {
  __hip_atomic_store(p, v, __ATOMIC_RELAXED, __HIP_MEMORY_SCOPE_SYSTEM);
}

// Wave-parallel slot poll: lanes 0-31 check s0[lane]>=n0, lanes 32-63 check
// s1[lane-32]>=n1, lanes 0-7 additionally check sf[lane]>=nf.
static __device__ __forceinline__ void poll_flags(const int* s0, const int* s1, const int* sf,
                                                  int n0, int n1, int nf) {
  if (threadIdx.x < 64) {
    const int lane = threadIdx.x;
    const int* p1 = (lane < 32) ? (s0 + lane * SLOT_STRIDE) : (s1 + (lane - 32) * SLOT_STRIDE);
    const int* p2 = sf + (lane & 7) * SLOT_STRIDE;
    const int need1 = (lane < 32) ? n0 : n1;
    const bool chk2 = (lane < 8);
    for (;;) {
      int v1 = flag_ld(p1);
      int v2 = flag_ld(p2);
      int ok = (v1 >= need1) && (!chk2 || (v2 >= nf));
      if (__all(ok)) break;
    }
  }
  __syncthreads();
}

// ---------------- prologue: pack weights bf16, transpose x, zero state ----------------
__global__ void lstm_prologue(
    const float* __restrict__ x, const float* __restrict__ wih0, const float* __restrict__ whh0,
    const float* __restrict__ wih1, const float* __restrict__ whh1, const float* __restrict__ wfc,
    unsigned short* __restrict__ wl0, unsigned short* __restrict__ wl1,
    unsigned short* __restrict__ wfcp, unsigned short* __restrict__ xb,
    unsigned short* __restrict__ h0r, unsigned short* __restrict__ h1r,
    int* __restrict__ flags) {
  size_t tid = (size_t)blockIdx.x * blockDim.x + threadIdx.x;
  size_t nthr = (size_t)gridDim.x * blockDim.x;
  for (size_t i = tid; i < (size_t)2048 * 768; i += nthr) {
    int r = (int)(i / 768), k = (int)(i % 768);
    float v = (k < 256) ? wih0[(size_t)r * 256 + k] : whh0[(size_t)r * 512 + (k - 256)];
    wl0[i] = f2b(v);
  }
  for (size_t i = tid; i < (size_t)2048 * 1024; i += nthr) {
    int r = (int)(i >> 10), k = (int)(i & 1023);
    float v = (k < 512) ? wih1[((size_t)r << 9) + k] : whh1[((size_t)r << 9) + (k - 512)];
    wl1[i] = f2b(v);
  }
  for (size_t i = tid; i < 131072; i += nthr) wfcp[i] = f2b(wfc[i]);
  // xb: [T][B][256] bf16 from x [B][T][256] f32
  for (size_t i = tid; i < (size_t)16777216; i += nthr) {
    int ii = (int)(i & 255), b = (int)((i >> 8) & 31), t = (int)(i >> 13);
    xb[i] = f2b(x[((size_t)b * 2048 + t) * 256 + ii]);
  }
  for (size_t i = tid; i < (NL0 + NL1 + NFC) * SLOT_STRIDE; i += nthr) flags[i] = 0;
  for (size_t i = tid; i < 32 * 512; i += nthr) {
    h0r[(size_t)(RING - 1) * 32 * 512 + i] = 0;
    h1r[(size_t)(RING - 1) * 32 * 512 + i] = 0;
  }
}

// ---------------- LSTM layer workgroup body (weight-stationary regs) ----------------
template <int ISL0>
static __device__ void lstm_path(
    const unsigned short* __restrict__ xb, const unsigned short* __restrict__ wl,
    const float* __restrict__ bias,
    unsigned short* __restrict__ h0r, unsigned short* __restrict__ h1r,
    int* s0, int* s1, int* sf, int wid2,
    unsigned short* hA, unsigned short* xA, float (*gates)[32][18]) {
  const int tid = threadIdx.x;
  const int wave = tid >> 6, lane = tid & 63, l15 = lane & 15, kgrp = lane >> 4;
  const int u0 = wid2 * 16;
  constexpr int K = ISL0 ? 768 : 1024;
  constexpr int NKW = ISL0 ? 24 : 32;  // weight k-tile fragments
  const unsigned short* wrow = wl + (size_t)(wave * 512 + u0 + l15) * K;

  // weight-stationary fragments: read once, live in VGPRs for the whole sequence
  bf16x8 wf[NKW];
#pragma unroll
  for (int kk = 0; kk < NKW; ++kk) wf[kk] = *(const bf16x8*)(wrow + kk * 32 + kgrp * 8);

  const int ue = 2 * (tid & 7);
  const int be = tid >> 3;
  const float bi0 = bias[0 * 512 + u0 + ue], bi1 = bias[0 * 512 + u0 + ue + 1];
  const float bf0 = bias[1 * 512 + u0 + ue], bf1 = bias[1 * 512 + u0 + ue + 1];
  const float bg0 = bias[2 * 512 + u0 + ue], bg1 = bias[2 * 512 + u0 + ue + 1];
  const float bo0 = bias[3 * 512 + u0 + ue], bo1 = bias[3 * 512 + u0 + ue + 1];
  float cc0 = 0.f, cc1 = 0.f;
  unsigned short* myring = ISL0 ? h0r : h1r;
  int* myslot = (ISL0 ? s0 : s1) + wid2 * SLOT_STRIDE;

  for (int t = 0; t < T_SEQ; ++t) {
    // L0: prefetch x fragments for step t (static data, issued before the poll)
    bf16x8 xf0[8], xf1[8];
    if (ISL0) {
      const unsigned short* xt = xb + (size_t)t * (32 * 256);
#pragma unroll
      for (int kk = 0; kk < 8; ++kk) {
        xf0[kk] = *(const bf16x8*)(xt + l15 * 256 + kk * 32 + kgrp * 8);
        xf1[kk] = *(const bf16x8*)(xt + (16 + l15) * 256 + kk * 32 + kgrp * 8);
      }
    }

    if (ISL0) {
      // peers' h0[t-1] ready; L1 consumed h0[t-RING] (ring guard via s1)
      poll_flags(s0, s1, sf, t, t - (RING - 1), -1000000);
    } else {
      // h0[t] ready; peers' h1[t-1] ready; FC consumed h1[t-RING]
      poll_flags(s0, s1, sf, t + 1, t, t - (RING - 1));
    }

    // ---- stage h tiles LDS <- LLC (one batched latency) ----
    const unsigned short* hprev = myring + (size_t)((t - 1) & (RING - 1)) * (32 * 512);
    u32x4 th[8], tx[8];
#pragma unroll
    for (int k = 0; k < 8; ++k)
      th[k] = llc_load16((const char*)hprev + (size_t)(tid + k * 256) * 16);
    if (!ISL0) {
      const unsigned short* h0cur = h0r + (size_t)(t & (RING - 1)) * (32 * 512);
#pragma unroll
      for (int k = 0; k < 8; ++k)
        tx[k] = llc_load16((const char*)h0cur + (size_t)(tid + k * 256) * 16);
    }
    vmwait();
#pragma unroll
    for (int k = 0; k < 8; ++k) {
      int off = (tid + k * 256) * 16;
      *(u32x4*)((char*)hA + HSWZ(off)) = th[k];
    }
    if (!ISL0) {
#pragma unroll
      for (int k = 0; k < 8; ++k) {
        int off = (tid + k * 256) * 16;
        *(u32x4*)((char*)xA + HSWZ(off)) = tx[k];
      }
    }
    __syncthreads();

    // ---- gates MFMA: weights from registers, activations from regs/LDS ----
    f32x4 acc0 = {0.f, 0.f, 0.f, 0.f}, acc1 = {0.f, 0.f, 0.f, 0.f};
    if (ISL0) {
#pragma unroll
      for (int kk = 0; kk < 8; ++kk) {
        acc0 = __builtin_amdgcn_mfma_f32_16x16x32_bf16(xf0[kk], wf[kk], acc0, 0, 0, 0);
        acc1 = __builtin_amdgcn_mfma_f32_16x16x32_bf16(xf1[kk], wf[kk], acc1, 0, 0, 0);
      }
#pragma unroll
      for (int kk = 0; kk < 16; ++kk) {
        int cb = (kk * 32 + kgrp * 8) * 2;
        bf16x8 a0 = *(const bf16x8*)((const char*)hA + HSWZ(l15 * 1024 + cb));
        bf16x8 a1 = *(const bf16x8*)((const char*)hA + HSWZ((16 + l15) * 1024 + cb));
        acc0 = __builtin_amdgcn_mfma_f32_16x16x32_bf16(a0, wf[8 + kk], acc0, 0, 0, 0);
        acc1 = __builtin_amdgcn_mfma_f32_16x16x32_bf16(a1, wf[8 + kk], acc1, 0, 0, 0);
      }
    } else {
#pragma unroll
      for (int kk = 0; kk < 16; ++kk) {
        int cb = (kk * 32 + kgrp * 8) * 2;
        bf16x8 a0 = *(const bf16x8*)((const char*)xA + HSWZ(l15 * 1024 + cb));
        bf16x8 a1 = *(const bf16x8*)((const char*)xA + HSWZ((16 + l15) * 1024 + cb));
        acc0 = __builtin_amdgcn_mfma_f32_16x16x32_bf16(a0, wf[kk], acc0, 0, 0, 0);
        acc1 = __builtin_amdgcn_mfma_f32_16x16x32_bf16(a1, wf[kk], acc1, 0, 0, 0);
      }
#pragma unroll
      for (int kk = 0; kk < 16; ++kk) {
        int cb = (kk * 32 + kgrp * 8) * 2;
        bf16x8 a0 = *(const bf16x8*)((const char*)hA + HSWZ(l15 * 1024 + cb));
        bf16x8 a1 = *(const bf16x8*)((const char*)hA + HSWZ((16 + l15) * 1024 + cb));
        acc0 = __builtin_amdgcn_mfma_f32_16x16x32_bf16(a0, wf[16 + kk], acc0, 0, 0, 0);
        acc1 = __builtin_amdgcn_mfma_f32_16x16x32_bf16(a1, wf[16 + kk], acc1, 0, 0, 0);
      }
    }
    // C/D: col(l15)=unit, row(kgrp*4+j)=batch.  gates[gate][batch][unit]
#pragma unroll
    for (int j = 0; j < 4; ++j) {
      gates[wave][kgrp * 4 + j][l15] = acc0[j];
      gates[wave][16 + kgrp * 4 + j][l15] = acc1[j];
    }
    __syncthreads();

    // ---- epilogue: 2 units x 1 batch per thread; c stays in registers ----
    unsigned short* hdst = myring + (size_t)(t & (RING - 1)) * (32 * 512);
    float i0 = sigm(gates[0][be][ue] + bi0);
    float ff0 = sigm(gates[1][be][ue] + bf0);
    float g0 = tanh_f(gates[2][be][ue] + bg0);
    float o0 = sigm(gates[3][be][ue] + bo0);
    cc0 = ff0 * cc0 + i0 * g0;
    float hv0 = o0 * tanh_f(cc0);
    float i1 = sigm(gates[0][be][ue + 1] + bi1);
    float ff1 = sigm(gates[1][be][ue + 1] + bf1);
    float g1 = tanh_f(gates[2][be][ue + 1] + bg1);
    float o1 = sigm(gates[3][be][ue + 1] + bo1);
    cc1 = ff1 * cc1 + i1 * g1;
    float hv1 = o1 * tanh_f(cc1);
    unsigned pv = (unsigned)f2b(hv0) | ((unsigned)f2b(hv1) << 16);
    llc_store4(hdst + (size_t)be * 512 + u0 + ue, pv);
    vmwait();            // this thread's h at LLC
    __syncthreads();     // all threads' h at LLC
    if (tid == 0) flag_st(myslot, t + 1);
  }
}

// ---------------- main persistent pipelined kernel ----------------
__global__ void __launch_bounds__(256) lstm_main(
    const unsigned short* __restrict__ xb,
    const unsigned short* __restrict__ wl0,
    const unsigned short* __restrict__ wl1,
    const unsigned short* __restrict__ wfcp,
    const float* __restrict__ b0,
    const float* __restrict__ b1,
    const float* __restrict__ bfc,
    unsigned short* __restrict__ h0r,
    unsigned short* __restrict__ h1r,
    int* flags,
    float* __restrict__ out) {
  __shared__ __align__(16) unsigned short hA[32 * 512];
  __shared__ __align__(16) unsigned short xA[32 * 512];
  __shared__ __align__(16) float gates[4][32][18];
  const int tid = threadIdx.x;
  const int wave = tid >> 6, lane = tid & 63, l15 = lane & 15, kgrp = lane >> 4;
  const int wid = blockIdx.x;
  int* s0 = flags;
  int* s1 = flags + NL0 * SLOT_STRIDE;
  int* sf = flags + (NL0 + NL1) * SLOT_STRIDE;

  if (wid < NL0) {
    lstm_path<1>(xb, wl0, b0, h0r, h1r, s0, s1, sf, wid, hA, xA, gates);
  } else if (wid < NL0 + NL1) {
    lstm_path<0>(xb, wl1, b1, h0r, h1r, s0, s1, sf, wid - NL0, hA, xA, gates);
  } else {
    const int fcw = wid - NL0 - NL1;  // 0..7
    const int mt = wave >> 1, ntile = wave & 1;
    const int orow = fcw * 32 + ntile * 16 + l15;
    bf16x8 wff[16];
#pragma unroll
    for (int kk = 0; kk < 16; ++kk)
      wff[kk] = *(const bf16x8*)(wfcp + (size_t)orow * 512 + kk * 32 + kgrp * 8);
    const float bb = bfc[orow];
    for (int t = 0; t < T_SEQ; ++t) {
      poll_flags(s0, s1, sf, -1000000, t + 1, -1000000);
      const unsigned short* hcur = h1r + (size_t)(t & (RING - 1)) * (32 * 512);
      u32x4 th[8];
#pragma unroll
      for (int k = 0; k < 8; ++k)
        th[k] = llc_load16((const char*)hcur + (size_t)(tid + k * 256) * 16);
      vmwait();
#pragma unroll
      for (int k = 0; k < 8; ++k) {
        int off = (tid + k * 256) * 16;
        *(u32x4*)((char*)hA + HSWZ(off)) = th[k];
      }
      __syncthreads();
      if (tid == 0) flag_st(sf + fcw * SLOT_STRIDE, t + 1);  // h1[t] consumed
      f32x4 acc = {0.f, 0.f, 0.f, 0.f};
#pragma unroll
      for (int kk = 0; kk < 16; ++kk) {
        int row = mt * 16 + l15;
        bf16x8 a = *(const bf16x8*)((const char*)hA + HSWZ(row * 1024 + (kk * 32 + kgrp * 8) * 2));
        acc = __builtin_amdgcn_mfma_f32_16x16x32_bf16(a, wff[kk], acc, 0, 0, 0);
      }
#pragma unroll
      for (int j = 0; j < 4; ++j) {
        int b = mt * 16 + kgrp * 4 + j;
        out[((size_t)b * T_SEQ + t) * 256 + orow] = acc[j] + bb;
      }
    }
  }
}

extern "C" void kernel_launch(void* const* d_in, const int* in_sizes, int n_in,
                              void* d_out, int out_size, void* d_ws, size_t ws_size,
                              hipStream_t stream) {
  const float* x    = (const float*)d_in[0];
  const float* wih0 = (const float*)d_in[1];
  const float* whh0 = (const float*)d_in[2];
  const float* b0   = (const float*)d_in[3];
  const float* wih1 = (const float*)d_in[4];
  const float* whh1 = (const float*)d_in[5];
  const float* b1   = (const float*)d_in[6];
  const float* wfc  = (const float*)d_in[7];
  const float* bfc  = (const float*)d_in[8];
  float* outp = (float*)d_out;

  char* ws = (char*)d_ws;
  size_t off = 0;
  unsigned short* wl0p = (unsigned short*)(ws + off); off += (size_t)2048 * 768 * 2;
  unsigned short* wl1p = (unsigned short*)(ws + off); off += (size_t)2048 * 1024 * 2;
  unsigned short* wfcp = (unsigned short*)(ws + off); off += (size_t)256 * 512 * 2;
  unsigned short* xbp  = (unsigned short*)(ws + off); off += (size_t)2048 * 32 * 256 * 2;
  unsigned short* h0rp = (unsigned short*)(ws + off); off += (size_t)RING * 32 * 512 * 2;
  unsigned short* h1rp = (unsigned short*)(ws + off); off += (size_t)RING * 32 * 512 * 2;
  int* flagsp = (int*)(ws + off); off += (size_t)NWG * SLOT_STRIDE * sizeof(int);

  lstm_prologue<<<dim3(1024), dim3(256), 0, stream>>>(
      x, wih0, whh0, wih1, whh1, wfc, wl0p, wl1p, wfcp, xbp, h0rp, h1rp, flagsp);

  // Plain launch: co-residency is structural (72 blocks <= 256 CUs at >=1
  // block/CU), and we use no grid.sync — cooperative launch's occupancy
  // validation (the round-3/4 silent-failure suspect) is not needed.
  lstm_main<<<dim3(NWG), dim3(256), 0, stream>>>(
      xbp, wl0p, wl1p, wfcp, b0, b1, bfc, h0rp, h1rp, flagsp, outp);
}